// Round 12
// baseline (299.046 us; speedup 1.0000x reference)
//
#include <hip/hip_runtime.h>
#include <math.h>
#include <stdint.h>

namespace {
constexpr float kDT  = 0.01f;   // DT / SUBSTEP, SUBSTEP == 1
constexpr int   kIter = 10;
constexpr float kH   = -2.0f;
constexpr float kEps = 1e-5f;
constexpr int   kB = 8;
constexpr int   kN = 50000;
constexpr int   kE = 200000;
constexpr int   kBN = kB * kN;
constexpr int   kNB = (kN + 255) / 256;   // 196 blocks for per-vertex kernels
}

// ---------------- CSR build (once per launch) ----------------

__global__ void count_kernel(const int2* __restrict__ Cdist, int* __restrict__ counts) {
    int e = blockIdx.x * blockDim.x + threadIdx.x;
    if (e >= kE) return;
    int2 c = Cdist[e];
    atomicAdd(&counts[c.x], 1);
    atomicAdd(&counts[c.y], 1);
}

__global__ void partial_sum_kernel(const int* __restrict__ in, int* __restrict__ blkSum) {
    __shared__ int s[256];
    int i = blockIdx.x * 256 + threadIdx.x;
    s[threadIdx.x] = (i < kN) ? in[i] : 0;
    __syncthreads();
    for (int off = 128; off > 0; off >>= 1) {
        if (threadIdx.x < off) s[threadIdx.x] += s[threadIdx.x + off];
        __syncthreads();
    }
    if (threadIdx.x == 0) blkSum[blockIdx.x] = s[0];
}

__global__ void scan_sums_kernel(const int* __restrict__ blkSum, int* __restrict__ blkOff) {
    __shared__ int s[kNB];
    int tid = threadIdx.x;                 // 256 threads >= kNB
    if (tid < kNB) s[tid] = blkSum[tid];
    __syncthreads();
    if (tid == 0) {
        int acc = 0;
        for (int i = 0; i < kNB; ++i) { int v = s[i]; s[i] = acc; acc += v; }
    }
    __syncthreads();
    if (tid < kNB) blkOff[tid] = s[tid];
}

__global__ void scatter_scan_kernel(const int* __restrict__ in,
                                    const int* __restrict__ blkOff,
                                    int* __restrict__ out) {
    __shared__ int s[256];
    int tid = threadIdx.x;
    int i = blockIdx.x * 256 + tid;
    int c = (i < kN) ? in[i] : 0;
    s[tid] = c;
    __syncthreads();
    for (int off = 1; off < 256; off <<= 1) {      // inclusive Hillis-Steele
        int v = (tid >= off) ? s[tid - off] : 0;
        __syncthreads();
        s[tid] += v;
        __syncthreads();
    }
    int incl = s[tid];
    int excl = incl - c;
    if (i < kN) out[i] = blkOff[blockIdx.x] + excl;
    if (i == kN - 1) out[kN] = blkOff[blockIdx.x] + incl;   // == 2E
}

// inc id = 2*e + side. Atomic fill order only permutes slot order within a
// vertex; summation-order FP wiggle is far below tolerance (validated R1-R11).
__global__ void fill_kernel(const int2* __restrict__ Cdist, int* __restrict__ cursor,
                            int* __restrict__ inc) {
    int e = blockIdx.x * blockDim.x + threadIdx.x;
    if (e >= kE) return;
    int2 c = Cdist[e];
    int p0 = atomicAdd(&cursor[c.x], 1);
    inc[p0] = 2 * e;
    int p1 = atomicAdd(&cursor[c.y], 1);
    inc[p1] = 2 * e + 1;
}

// Per-slot static data: SS[k] = {other vertex, init_d bits}. No per-batch data.
__global__ void slots_build_kernel(const int* __restrict__ inc,
                                   const int2* __restrict__ Cdist,
                                   const float* __restrict__ Cinit,
                                   int2* __restrict__ SS) {
    int k = blockIdx.x * blockDim.x + threadIdx.x;
    if (k >= 2 * kE) return;
    int ic = inc[k];
    int e = ic >> 1;
    int2 c = Cdist[e];
    int other = (ic & 1) ? c.x : c.y;
    SS[k] = make_int2(other, __float_as_int(Cinit[e]));
}

// ---------------- predict + batch-minor re-layout ----------------

// P[v][b] = {x,y,z predicted, w};  Cf[v][b] = compliance (1.6 MB, L2-resident)
__global__ void predict_kernel(const float* __restrict__ V,
                               const float* __restrict__ Vvel,
                               const float* __restrict__ Vw,
                               const float* __restrict__ Vcomp,
                               const float* __restrict__ Vmass,
                               const float* __restrict__ Vforce,
                               float4* __restrict__ P,
                               float* __restrict__ Cf) {
    int v = blockIdx.x * blockDim.x + threadIdx.x;
    if (v >= kN) return;
#pragma unroll
    for (int b = 0; b < kB; ++b) {
        int idx = b * kN + v;
        int k = idx * 3;
        float m = Vmass[idx];
        float4 r;
        float vpx = Vvel[k + 0] + (kDT * Vforce[k + 0]) / m;   // (dt*F)/m, reference order
        float vpy = Vvel[k + 1] + (kDT * Vforce[k + 1]) / m;
        float vpz = Vvel[k + 2] + (kDT * Vforce[k + 2]) / m;
        r.x = V[k + 0] + kDT * vpx;
        r.y = V[k + 1] + kDT * vpy;
        r.z = V[k + 2] + kDT * vpz;
        r.w = Vw[idx];
        P[(size_t)v * 8 + b] = r;
        Cf[(size_t)v * 8 + b] = Vcomp[idx];
    }
}

// ---------------- fused Jacobi sweep ----------------
// Thread = (vertex v, batch b = lane&7): own/dst P and the neighbor gather are
// full 64B/128B lines shared by the 8 lanes; SS broadcasts; L is 32B runs.
// Each vertex recomputes its incident edges' corrections (Ld is bitwise
// identical from either endpoint: sign cancels in squares; comp/w adds
// commute), so no edge->vertex communication; per-slot L is owned by exactly
// one thread. A = (comp_own + comp_oth)/2 from the 1.6MB L2-resident comp
// table; rSA = 1/(S+A) with S = own.w + oth.w (S==0 -> Ld=0 matches inf).
// k-loop is 2-wide software-pipelined: both P gathers issue before compute.
// PHASE: 0 = first sweep (L assumed 0, not read), 1 = middle, 2 = last
// (plane-collision + velocity fused, writes d_out).
__device__ __forceinline__ void edge_op(const float4& own, const float4& oth,
                                        float A, float Lold, float initd,
                                        float* Lout,
                                        float& ax, float& ay, float& az) {
    float dx = own.x - oth.x;
    float dy = own.y - oth.y;
    float dz = own.z - oth.z;
    float D = sqrtf(dx * dx + dy * dy + dz * dz);
    float C = D - initd;
    float S = own.w + oth.w;
    float rSA = (S == 0.0f) ? 0.0f : 1.0f / (S + A);
    float Ld = (-C - A * Lold) * rSA;
    *Lout = Lold + Ld;
    float rD = 1.0f / D;
    ax += Ld * (dx * rD);
    ay += Ld * (dy * rD);
    az += Ld * (dz * rD);
}

template <int PHASE>
__global__ __launch_bounds__(256)
void sweep_kernel(const float4* __restrict__ Psrc,
                  float4* __restrict__ Pdst,
                  float* __restrict__ L,
                  const float* __restrict__ Cf,
                  const int2* __restrict__ SS,
                  const int* __restrict__ start,
                  const float* __restrict__ V,
                  float* __restrict__ outV,
                  float* __restrict__ outVel) {
    int t = blockIdx.x * blockDim.x + threadIdx.x;
    if (t >= 8 * kN) return;
    int v = t >> 3;
    int b = t & 7;
    float4 own = Psrc[(size_t)v * 8 + b];
    float co = Cf[(size_t)v * 8 + b];
    int s0 = start[v], s1 = start[v + 1];
    float ax = 0.f, ay = 0.f, az = 0.f;

    int k = s0;
    for (; k + 1 < s1; k += 2) {
        int2 ss0 = SS[k];
        int2 ss1 = SS[k + 1];
        float4 o0 = Psrc[(size_t)ss0.x * 8 + b];   // two independent gathers
        float4 o1 = Psrc[(size_t)ss1.x * 8 + b];   // in flight together
        float c0 = Cf[(size_t)ss0.x * 8 + b];      // L2-resident table
        float c1 = Cf[(size_t)ss1.x * 8 + b];
        float L0 = (PHASE == 0) ? 0.0f : L[(size_t)k * 8 + b];
        float L1 = (PHASE == 0) ? 0.0f : L[(size_t)(k + 1) * 8 + b];
        edge_op(own, o0, (co + c0) * 0.5f, L0, __int_as_float(ss0.y),
                &L[(size_t)k * 8 + b], ax, ay, az);
        edge_op(own, o1, (co + c1) * 0.5f, L1, __int_as_float(ss1.y),
                &L[(size_t)(k + 1) * 8 + b], ax, ay, az);
    }
    if (k < s1) {
        int2 ss = SS[k];
        float4 o = Psrc[(size_t)ss.x * 8 + b];
        float cc = Cf[(size_t)ss.x * 8 + b];
        float Lold = (PHASE == 0) ? 0.0f : L[(size_t)k * 8 + b];
        edge_op(own, o, (co + cc) * 0.5f, Lold, __int_as_float(ss.y),
                &L[(size_t)k * 8 + b], ax, ay, az);
    }

    float px = own.x + own.w * ax;
    float py = own.y + own.w * ay;
    float pz = own.z + own.w * az;
    if (PHASE != 2) {
        Pdst[(size_t)v * 8 + b] = make_float4(px, py, pz, own.w);
    } else {
        int k3 = (b * kN + v) * 3;
        float vx = V[k3], vy = V[k3 + 1], vz0 = V[k3 + 2];

        bool col = (pz < kH) && (vz0 > kH);
        float h_prev = vz0 - kH;
        float h_after = kH - pz;
        float denom = col ? (h_prev + h_after) : 1.0f;
        float tt = h_prev / denom;

        float x  = col ? (vx + tt * (px - vx)) : px;
        float y  = col ? (vy + tt * (py - vy)) : py;
        float z1 = col ? (kH + kEps) : pz;

        bool vio = (z1 < kH) && (vz0 < kH);
        float z2 = vio ? (kH + kEps) : z1;

        float velx = (x  - vx ) / kDT;
        float vely = (y  - vy ) / kDT;
        float velz = (z2 - vz0) / kDT;
        velz = col ? -velz : velz;
        velz = vio ? 0.0f : velz;

        outV[k3] = x;  outV[k3 + 1] = y;  outV[k3 + 2] = z2;
        outVel[k3] = velx; outVel[k3 + 1] = vely; outVel[k3 + 2] = velz;
    }
}

// ---------------- launch ----------------

extern "C" void kernel_launch(void* const* d_in, const int* in_sizes, int n_in,
                              void* d_out, int out_size, void* d_ws, size_t ws_size,
                              hipStream_t stream) {
    const float* V      = (const float*)d_in[0];
    const float* Vvel   = (const float*)d_in[1];
    const float* Vw     = (const float*)d_in[2];
    const float* Vcomp  = (const float*)d_in[3];
    const float* Vmass  = (const float*)d_in[4];
    const float* Vforce = (const float*)d_in[5];
    const float* Cinit  = (const float*)d_in[6];
    const int2*  Cdist  = (const int2*)d_in[7];

    char* p = (char*)d_ws;
    auto alloc = [&](size_t bytes) -> void* {
        p = (char*)(((uintptr_t)p + 255) & ~(uintptr_t)255);
        void* r = (void*)p;
        p += bytes;
        return r;
    };

    float4* PA     = (float4*)alloc((size_t)kN * 8 * sizeof(float4));       // 6.4 MB
    float4* PB     = (float4*)alloc((size_t)kN * 8 * sizeof(float4));       // 6.4 MB
    float*  L      = (float*)alloc((size_t)2 * kE * 8 * sizeof(float));     // 12.8 MB
    int2*   SS     = (int2*)alloc((size_t)2 * kE * sizeof(int2));           // 3.2 MB
    float*  Cf     = (float*)alloc((size_t)kN * 8 * sizeof(float));         // 1.6 MB
    int*    start  = (int*)alloc((size_t)(kN + 1) * sizeof(int));
    int*    cursor = (int*)alloc((size_t)kN * sizeof(int));
    int*    inc    = (int*)alloc((size_t)2 * kE * sizeof(int));
    int*    blkSum = (int*)alloc((size_t)kNB * sizeof(int));
    int*    blkOff = (int*)alloc((size_t)kNB * sizeof(int));

    const int TB = 256;
    dim3 blk(TB);
    dim3 gE((kE + TB - 1) / TB);
    dim3 g2E((2 * kE + TB - 1) / TB);
    dim3 gN(kNB);
    dim3 g8N((8 * kN + TB - 1) / TB);

    // CSR build (cursor doubles as counts)
    hipMemsetAsync(cursor, 0, kN * sizeof(int), stream);
    count_kernel<<<gE, blk, 0, stream>>>(Cdist, cursor);
    partial_sum_kernel<<<gN, blk, 0, stream>>>(cursor, blkSum);
    scan_sums_kernel<<<dim3(1), blk, 0, stream>>>(blkSum, blkOff);
    scatter_scan_kernel<<<gN, blk, 0, stream>>>(cursor, blkOff, start);
    hipMemcpyAsync(cursor, start, kN * sizeof(int), hipMemcpyDeviceToDevice, stream);
    fill_kernel<<<gE, blk, 0, stream>>>(Cdist, cursor, inc);
    slots_build_kernel<<<g2E, blk, 0, stream>>>(inc, Cdist, Cinit, SS);

    // predict + batch-minor layout (no L memset: PHASE 0 writes without reading)
    predict_kernel<<<gN, blk, 0, stream>>>(V, Vvel, Vw, Vcomp, Vmass, Vforce, PA, Cf);

    float* outV   = (float*)d_out;
    float* outVel = outV + (size_t)kBN * 3;

    for (int it = 0; it < kIter; ++it) {
        float4* src = (it & 1) ? PB : PA;
        float4* dst = (it & 1) ? PA : PB;
        if (it == 0) {
            sweep_kernel<0><<<g8N, blk, 0, stream>>>(src, dst, L, Cf, SS, start,
                                                     V, outV, outVel);
        } else if (it < kIter - 1) {
            sweep_kernel<1><<<g8N, blk, 0, stream>>>(src, dst, L, Cf, SS, start,
                                                     V, outV, outVel);
        } else {
            sweep_kernel<2><<<g8N, blk, 0, stream>>>(src, dst, L, Cf, SS, start,
                                                     V, outV, outVel);
        }
    }
}